// Round 20
// baseline (285.178 us; speedup 1.0000x reference)
//
#include <hip/hip_runtime.h>
#include <hip/hip_bf16.h>

#define T_TOK 2048
#define H_DIM 2048
#define F_DIM 1408
#define N_EXP 8
#define BM 128
#define BN 64
#define BK 64

#define NITEM 40
#define G1_NY (F_DIM / BN)   // 22
#define G2_NY (H_DIM / BN)   // 32
#define G1_CHUNK ((NITEM * G1_NY) / 8)  // 110
#define G2_CHUNK ((NITEM * G2_NY) / 8)  // 160
#define WELEMS ((size_t)N_EXP * F_DIM * H_DIM)

typedef float f32x4 __attribute__((ext_vector_type(4)));
typedef short s16x8 __attribute__((ext_vector_type(8)));
typedef unsigned int u32;

// swizzled LDS byte offset: rows are 128B (64 bf16); XOR bits[4:6] with row&7
#define LOFF(row, kbyte) (((row) << 7) + ((kbyte) ^ (((row) & 7) << 4)))

__device__ __forceinline__ int bf2i(__hip_bfloat162 h) {
  int r; __builtin_memcpy(&r, &h, 4); return r;
}

__device__ __forceinline__ int4 pack8(float4 a, float4 b) {
  int4 r;
  r.x = bf2i(__float22bfloat162_rn(float2{a.x, a.y}));
  r.y = bf2i(__float22bfloat162_rn(float2{a.z, a.w}));
  r.z = bf2i(__float22bfloat162_rn(float2{b.x, b.y}));
  r.w = bf2i(__float22bfloat162_rn(float2{b.z, b.w}));
  return r;
}

__device__ __forceinline__ unsigned short f2bf(float f) {
  __hip_bfloat16 h = __float2bfloat16(f);
  unsigned short r; __builtin_memcpy(&r, &h, 2); return r;
}

__device__ __forceinline__ f32x4 mfma16(s16x8 a, s16x8 b, f32x4 c) {
  return __builtin_amdgcn_mfma_f32_16x16x32_bf16(a, b, c, 0, 0, 0);
}

// async global->LDS 16B per lane; LDS dest = wave-uniform base + lane*16
__device__ __forceinline__ void dma16(const unsigned short* g, unsigned short* l) {
  __builtin_amdgcn_global_load_lds((const __attribute__((address_space(1))) u32*)g,
                                   (__attribute__((address_space(3))) u32*)l, 16, 0, 0);
}

// ---------------- weight cast f32 -> bf16 (one launch, grid.y picks array) ----------------
__global__ void cast_w3(const float* __restrict__ wa, const float* __restrict__ wb,
                        const float* __restrict__ wc,
                        unsigned short* __restrict__ oa, unsigned short* __restrict__ ob,
                        unsigned short* __restrict__ oc, int n8) {
  const float* in = (blockIdx.y == 0) ? wa : (blockIdx.y == 1) ? wb : wc;
  unsigned short* out = (blockIdx.y == 0) ? oa : (blockIdx.y == 1) ? ob : oc;
  int i = blockIdx.x * blockDim.x + threadIdx.x;
  const int stride = gridDim.x * blockDim.x;
  for (; i < n8; i += stride) {
    const float4 a = ((const float4*)in)[2 * i];
    const float4 b = ((const float4*)in)[2 * i + 1];
    ((int4*)out)[i] = pack8(a, b);
  }
}

// ---------------- router (+ fused x->bf16 cast) ----------------
__global__ void router_kernel(const float* __restrict__ x, const float* __restrict__ gw,
                              float* __restrict__ logits, int* __restrict__ tk_idx,
                              float* __restrict__ tk_w, unsigned short* __restrict__ xb) {
  __shared__ float xs[H_DIM];
  __shared__ float lg[N_EXP];
  const int t = blockIdx.x;
  const int tid = threadIdx.x;
  const float4 xv = ((const float4*)(x + (size_t)t * H_DIM))[tid];
  ((float4*)xs)[tid] = xv;
  int2 cw;
  cw.x = bf2i(__float22bfloat162_rn(float2{xv.x, xv.y}));
  cw.y = bf2i(__float22bfloat162_rn(float2{xv.z, xv.w}));
  ((int2*)(xb + (size_t)t * H_DIM))[tid] = cw;
  __syncthreads();
  const int w = tid >> 6, l = tid & 63;
  const float* g = gw + w * H_DIM;
  float s = 0.f;
  for (int j = l; j < H_DIM; j += 64) s += xs[j] * g[j];
#pragma unroll
  for (int o = 32; o; o >>= 1) s += __shfl_down(s, o);
  if (l == 0) lg[w] = s;
  __syncthreads();
  if (tid == 0) {
    float mx = lg[0];
#pragma unroll
    for (int i = 1; i < N_EXP; i++) mx = fmaxf(mx, lg[i]);
    float p[N_EXP];
#pragma unroll
    for (int i = 0; i < N_EXP; i++) p[i] = __expf(lg[i] - mx);
    int i0 = 0;
#pragma unroll
    for (int i = 1; i < N_EXP; i++) if (p[i] > p[i0]) i0 = i;
    int i1 = (i0 == 0) ? 1 : 0;
#pragma unroll
    for (int i = 0; i < N_EXP; i++) if (i != i0 && p[i] > p[i1]) i1 = i;
    const float ww = p[i0] + p[i1];
    tk_idx[t * 2] = i0; tk_idx[t * 2 + 1] = i1;
    tk_w[t * 2] = p[i0] / ww; tk_w[t * 2 + 1] = p[i1] / ww;
#pragma unroll
    for (int i = 0; i < N_EXP; i++) logits[t * N_EXP + i] = lg[i];
  }
}

// ---------------- deterministic per-expert list build (1 block/expert) ----------------
__global__ void build_lists(const int* __restrict__ tk_idx, const float* __restrict__ tk_w,
                            int* __restrict__ counts, int* __restrict__ entries,
                            float* __restrict__ wlist) {
  const int e = blockIdx.x;
  const int l = threadIdx.x;
  int base = 0;
  for (int t0 = 0; t0 < T_TOK; t0 += 64) {
    const int t = t0 + l;
    int sel = -1; float w = 0.f;
    const int i0 = tk_idx[t * 2], i1 = tk_idx[t * 2 + 1];
    if (i0 == e) { sel = t * 2; w = tk_w[t * 2]; }
    else if (i1 == e) { sel = t * 2 + 1; w = tk_w[t * 2 + 1]; }
    const unsigned long long mask = __ballot(sel >= 0);
    const int pos = base + __popcll(mask & ((1ull << l) - 1ull));
    if (sel >= 0) { entries[e * T_TOK + pos] = sel; wlist[e * T_TOK + pos] = w; }
    base += __popcll(mask);
  }
  if (l == 0) counts[e] = base;
}

// ---------------- dense work-item table ----------------
__global__ void build_items(const int* __restrict__ counts, int* __restrict__ items) {
  if (threadIdx.x == 0) {
    int n = 0;
#pragma unroll
    for (int e = 0; e < N_EXP; e++) {
      const int c = counts[e];
      for (int m0 = 0; m0 < c; m0 += BM) items[1 + n++] = (e << 16) | (m0 / BM);
    }
    items[0] = n;
  }
}

// ================= PATH A: bf16 weights, all-DMA, counted-vmcnt (T4) =================
// Step t: issue A(t+1) (2-buf), B(t+2) (3-buf); MFMA tile t; wait vmcnt(K)
// keeping B(t+2) in flight across the barrier (never drain to 0 in the loop).
__global__ __launch_bounds__(512)
void moe_gemm1b(const unsigned short* __restrict__ w1b, const unsigned short* __restrict__ w3b,
                const unsigned short* __restrict__ xb,
                const int* __restrict__ counts, const int* __restrict__ entries,
                const int* __restrict__ items,
                unsigned short* __restrict__ hb) {
  const int lin = blockIdx.x;
  const int virt = (lin & 7) * G1_CHUNK + (lin >> 3);
  const int ix = virt % NITEM;
  const int iy = virt / NITEM;
  if (ix >= items[0]) return;
  const int it = items[1 + ix];
  const int e = it >> 16;
  const int m0 = (it & 0xffff) * BM;
  const int rem = counts[e] - m0;
  const int n0 = iy * BN;

  __shared__ unsigned short sA[2][BM * BK];   // 2 x 16KB
  __shared__ unsigned short sB1[3][BN * BK];  // 3 x 8KB
  __shared__ unsigned short sB3[3][BN * BK];  // 3 x 8KB

  const int tid = threadIdx.x;
  const int lane = tid & 63;
  const int wave = tid >> 6;
  const int wm = wave >> 1, wn = wave & 1;

  const int* elist = entries + e * T_TOK + m0;

  const int gcolb = (((lane & 7) << 4) ^ (((lane >> 3) & 7) << 4));
  const int arow0 = wave * 16 + (lane >> 3);
  const int arow1 = arow0 + 8;
  const int tokA0 = elist[arow0 < rem ? arow0 : 0] >> 1;
  const int tokA1 = elist[arow1 < rem ? arow1 : 0] >> 1;
  const unsigned short* gaA0 = xb + (size_t)tokA0 * H_DIM + (gcolb >> 1);
  const unsigned short* gaA1 = xb + (size_t)tokA1 * H_DIM + (gcolb >> 1);
  const int awA = wave * 1024;  // u16

  const int rB = tid >> 3;
  const int gbcol = ((tid & 7) ^ (rB & 7)) * 8;  // u16
  const unsigned short* gb1 = w1b + ((size_t)e * F_DIM + n0 + rB) * H_DIM + gbcol;
  const unsigned short* gb3 = w3b + ((size_t)e * F_DIM + n0 + rB) * H_DIM + gbcol;
  const int awB = wave * 512;   // u16

  const int rowA0 = wm * 32 + (lane & 15);
  const int rowA1 = rowA0 + 16;
  const int rowB0 = wn * 32 + (lane & 15);
  const int rowB1 = rowB0 + 16;
  const int kb = (lane >> 4) * 16;

  const f32x4 zero = {0.f, 0.f, 0.f, 0.f};
  f32x4 aG[2][2], aU[2][2];
#pragma unroll
  for (int i = 0; i < 2; i++)
#pragma unroll
    for (int j = 0; j < 2; j++) { aG[i][j] = zero; aU[i][j] = zero; }

  // prologue: tile 0 -> a0/b[0]; drain; barrier; issue B(1)->b[1] (stays in flight)
  dma16(gaA0, sA[0] + awA);
  dma16(gaA1, sA[0] + awA + 512);
  dma16(gb1, sB1[0] + awB);
  dma16(gb3, sB3[0] + awB);
  asm volatile("s_waitcnt vmcnt(0)" ::: "memory");
  __builtin_amdgcn_s_barrier();
  dma16(gb1 + BK, sB1[1] + awB);
  dma16(gb3 + BK, sB3[1] + awB);

  const int NT = H_DIM / BK;  // 32
  int bi = 0;  // buffer index of tile t (mod 3)
  for (int t = 0; t < NT; ++t) {
    const int an = (t + 1) & 1;
    const int bw = (bi + 2 >= 3) ? (bi - 1) : (bi + 2);  // (t+2)%3
    const int ka = (t + 1 < NT) ? (t + 1) * BK : 0;
    const int kbv = (t + 2 < NT) ? (t + 2) * BK : 0;
    dma16(gaA0 + ka, sA[an] + awA);
    dma16(gaA1 + ka, sA[an] + awA + 512);
    dma16(gb1 + kbv, sB1[bw] + awB);
    dma16(gb3 + kbv, sB3[bw] + awB);
    __builtin_amdgcn_sched_barrier(0);
    __builtin_amdgcn_s_setprio(1);
    const char* aC = (const char*)sA[t & 1];
    const char* b1C = (const char*)sB1[bi];
    const char* b3C = (const char*)sB3[bi];
#pragma unroll
    for (int kk = 0; kk < 2; kk++) {
      const int kbyte = kk * 64 + kb;
      const s16x8 a0 = *(const s16x8*)(aC + LOFF(rowA0, kbyte));
      const s16x8 a1 = *(const s16x8*)(aC + LOFF(rowA1, kbyte));
      const s16x8 p0 = *(const s16x8*)(b1C + LOFF(rowB0, kbyte));
      const s16x8 p1 = *(const s16x8*)(b1C + LOFF(rowB1, kbyte));
      const s16x8 q0 = *(const s16x8*)(b3C + LOFF(rowB0, kbyte));
      const s16x8 q1 = *(const s16x8*)(b3C + LOFF(rowB1, kbyte));
      aG[0][0] = mfma16(a0, p0, aG[0][0]); aG[0][1] = mfma16(a0, p1, aG[0][1]);
      aG[1][0] = mfma16(a1, p0, aG[1][0]); aG[1][1] = mfma16(a1, p1, aG[1][1]);
      aU[0][0] = mfma16(a0, q0, aU[0][0]); aU[0][1] = mfma16(a0, q1, aU[0][1]);
      aU[1][0] = mfma16(a1, q0, aU[1][0]); aU[1][1] = mfma16(a1, q1, aU[1][1]);
    }
    __builtin_amdgcn_s_setprio(0);
    // drain B(t+1) (issued t-1) + A(t+1) (this step); keep B(t+2) in flight
    asm volatile("s_waitcnt vmcnt(2) lgkmcnt(0)" ::: "memory");
    __builtin_amdgcn_s_barrier();
    bi = (bi + 1 >= 3) ? 0 : (bi + 1);
  }

  // epilogue: h = silu(g)*u -> bf16 scatter by entry row
#pragma unroll
  for (int i = 0; i < 2; i++) {
#pragma unroll
    for (int r = 0; r < 4; r++) {
      const int m = wm * 32 + i * 16 + ((lane >> 4) << 2) + r;
      if (m < rem) {
        const int entry = elist[m];
        unsigned short* hp = hb + (size_t)entry * F_DIM + n0 + wn * 32 + (lane & 15);
#pragma unroll
        for (int j = 0; j < 2; j++) {
          const float g = aG[i][j][r];
          const float u = aU[i][j][r];
          hp[j * 16] = f2bf(g / (1.f + __expf(-g)) * u);
        }
      }
    }
  }
}

__global__ __launch_bounds__(512)
void moe_gemm2b(const unsigned short* __restrict__ w2b,
                const unsigned short* __restrict__ hb,
                const int* __restrict__ counts, const int* __restrict__ entries,
                const float* __restrict__ wlist, const int* __restrict__ items,
                float* __restrict__ out) {
  const int lin = blockIdx.x;
  const int virt = (lin & 7) * G2_CHUNK + (lin >> 3);
  const int ix = virt % NITEM;
  const int iy = virt / NITEM;
  if (ix >= items[0]) return;
  const int it = items[1 + ix];
  const int e = it >> 16;
  const int m0 = (it & 0xffff) * BM;
  const int rem = counts[e] - m0;
  const int n0 = iy * BN;

  __shared__ unsigned short sA[2][BM * BK];  // 2 x 16KB
  __shared__ unsigned short sB[3][BN * BK];  // 3 x 8KB

  const int tid = threadIdx.x;
  const int lane = tid & 63;
  const int wave = tid >> 6;
  const int wm = wave >> 1, wn = wave & 1;

  const int* elist = entries + e * T_TOK + m0;
  const float* wl = wlist + e * T_TOK + m0;

  const int gcolb = (((lane & 7) << 4) ^ (((lane >> 3) & 7) << 4));
  const int arow0 = wave * 16 + (lane >> 3);
  const int arow1 = arow0 + 8;
  const int enA0 = elist[arow0 < rem ? arow0 : 0];
  const int enA1 = elist[arow1 < rem ? arow1 : 0];
  const unsigned short* gaA0 = hb + (size_t)enA0 * F_DIM + (gcolb >> 1);
  const unsigned short* gaA1 = hb + (size_t)enA1 * F_DIM + (gcolb >> 1);
  const int awA = wave * 1024;

  const int rB = tid >> 3;
  const int gbcol = ((tid & 7) ^ (rB & 7)) * 8;
  const unsigned short* gb = w2b + ((size_t)e * H_DIM + n0 + rB) * F_DIM + gbcol;
  const int awB = wave * 512;

  const int rowA0 = wm * 32 + (lane & 15);
  const int rowA1 = rowA0 + 16;
  const int rowB0 = wn * 32 + (lane & 15);
  const int rowB1 = rowB0 + 16;
  const int kb = (lane >> 4) * 16;

  const f32x4 zero = {0.f, 0.f, 0.f, 0.f};
  f32x4 ac[2][2];
#pragma unroll
  for (int i = 0; i < 2; i++)
#pragma unroll
    for (int j = 0; j < 2; j++) ac[i][j] = zero;

  dma16(gaA0, sA[0] + awA);
  dma16(gaA1, sA[0] + awA + 512);
  dma16(gb, sB[0] + awB);
  asm volatile("s_waitcnt vmcnt(0)" ::: "memory");
  __builtin_amdgcn_s_barrier();
  dma16(gb + BK, sB[1] + awB);

  const int NT = F_DIM / BK;  // 22
  int bi = 0;
  for (int t = 0; t < NT; ++t) {
    const int an = (t + 1) & 1;
    const int bw = (bi + 2 >= 3) ? (bi - 1) : (bi + 2);
    const int ka = (t + 1 < NT) ? (t + 1) * BK : 0;
    const int kbv = (t + 2 < NT) ? (t + 2) * BK : 0;
    dma16(gaA0 + ka, sA[an] + awA);
    dma16(gaA1 + ka, sA[an] + awA + 512);
    dma16(gb + kbv, sB[bw] + awB);
    __builtin_amdgcn_sched_barrier(0);
    __builtin_amdgcn_s_setprio(1);
    const char* aC = (const char*)sA[t & 1];
    const char* bC = (const char*)sB[bi];
#pragma unroll
    for (int kk = 0; kk < 2; kk++) {
      const int kbyte = kk * 64 + kb;
      const s16x8 a0 = *(const s16x8*)(aC + LOFF(rowA0, kbyte));
      const s16x8 a1 = *(const s16x8*)(aC + LOFF(rowA1, kbyte));
      const s16x8 f0 = *(const s16x8*)(bC + LOFF(rowB0, kbyte));
      const s16x8 f1 = *(const s16x8*)(bC + LOFF(rowB1, kbyte));
      ac[0][0] = mfma16(a0, f0, ac[0][0]); ac[0][1] = mfma16(a0, f1, ac[0][1]);
      ac[1][0] = mfma16(a1, f0, ac[1][0]); ac[1][1] = mfma16(a1, f1, ac[1][1]);
    }
    __builtin_amdgcn_s_setprio(0);
    asm volatile("s_waitcnt vmcnt(1) lgkmcnt(0)" ::: "memory");
    __builtin_amdgcn_s_barrier();
    bi = (bi + 1 >= 3) ? 0 : (bi + 1);
  }

#pragma unroll
  for (int i = 0; i < 2; i++) {
#pragma unroll
    for (int r = 0; r < 4; r++) {
      const int m = wm * 32 + i * 16 + ((lane >> 4) << 2) + r;
      if (m < rem) {
        const int entry = elist[m];
        const int tok = entry >> 1;
        const float wgt = wl[m];
        float* op = out + (size_t)tok * H_DIM + n0 + wn * 32 + (lane & 15);
#pragma unroll
        for (int j = 0; j < 2; j++) atomicAdd(op + j * 16, wgt * ac[i][j][r]);
      }
    }
  }
}

extern "C" void kernel_launch(void* const* d_in, const int* in_sizes, int n_in,
                              void* d_out, int out_size, void* d_ws, size_t ws_size,
                              hipStream_t stream) {
  const float* x  = (const float*)d_in[0];
  const float* gw = (const float*)d_in[1];
  const float* w1 = (const float*)d_in[2];
  const float* w3 = (const float*)d_in[3];
  const float* w2 = (const float*)d_in[4];
  float* out = (float*)d_out;
  float* logits = out + (size_t)T_TOK * H_DIM;

  char* ws = (char*)d_ws;
  size_t off = 0;
  unsigned short* xb = (unsigned short*)(ws + off); off += (size_t)T_TOK * H_DIM * 2;
  unsigned short* hb = (unsigned short*)(ws + off); off += (size_t)T_TOK * 2 * F_DIM * 2;
  int*   tk_idx = (int*)(ws + off);   off += (size_t)T_TOK * 2 * 4;
  float* tk_w   = (float*)(ws + off); off += (size_t)T_TOK * 2 * 4;
  int*   counts = (int*)(ws + off);   off += 256;
  int*   entries = (int*)(ws + off);  off += (size_t)N_EXP * T_TOK * 4;
  float* wlist  = (float*)(ws + off); off += (size_t)N_EXP * T_TOK * 4;
  int*   items  = (int*)(ws + off);   off += 256;
  unsigned short* w1b = (unsigned short*)(ws + off); off += WELEMS * 2;
  unsigned short* w3b = (unsigned short*)(ws + off); off += WELEMS * 2;
  unsigned short* w2b = (unsigned short*)(ws + off); off += WELEMS * 2;

  (void)hipMemsetAsync(d_out, 0, (size_t)out_size * sizeof(float), stream);
  const int n8 = (int)(WELEMS / 8);
  cast_w3<<<dim3(2048, 3), 256, 0, stream>>>(w1, w3, w2, w1b, w3b, w2b, n8);
  router_kernel<<<dim3(T_TOK), 512, 0, stream>>>(x, gw, logits, tk_idx, tk_w, xb);
  build_lists<<<dim3(N_EXP), 64, 0, stream>>>(tk_idx, tk_w, counts, entries, wlist);
  build_items<<<dim3(1), 64, 0, stream>>>(counts, items);
  moe_gemm1b<<<dim3(NITEM * G1_NY), 512, 0, stream>>>(w1b, w3b, xb, counts, entries, items, hb);
  moe_gemm2b<<<dim3(NITEM * G2_NY), 512, 0, stream>>>(w2b, hb, counts, entries, wlist, items, out);
}

// Round 21
// 257.730 us; speedup vs baseline: 1.1065x; 1.1065x over previous
//
#include <hip/hip_runtime.h>
#include <hip/hip_bf16.h>

#define T_TOK 2048
#define H_DIM 2048
#define F_DIM 1408
#define N_EXP 8
#define BM 128
#define BN 64
#define BK 64

#define NITEM 40
#define G1_NY (F_DIM / BN)   // 22
#define G2_NY (H_DIM / BN)   // 32
#define G1_CHUNK ((NITEM * G1_NY) / 8)  // 110
#define G2_CHUNK ((NITEM * G2_NY) / 8)  // 160
#define WELEMS ((size_t)N_EXP * F_DIM * H_DIM)

typedef float f32x4 __attribute__((ext_vector_type(4)));
typedef short s16x8 __attribute__((ext_vector_type(8)));
typedef unsigned int u32;

// swizzled LDS byte offset: rows are 128B (64 bf16); XOR bits[4:6] with row&7
#define LOFF(row, kbyte) (((row) << 7) + ((kbyte) ^ (((row) & 7) << 4)))

__device__ __forceinline__ int bf2i(__hip_bfloat162 h) {
  int r; __builtin_memcpy(&r, &h, 4); return r;
}

__device__ __forceinline__ int4 pack8(float4 a, float4 b) {
  int4 r;
  r.x = bf2i(__float22bfloat162_rn(float2{a.x, a.y}));
  r.y = bf2i(__float22bfloat162_rn(float2{a.z, a.w}));
  r.z = bf2i(__float22bfloat162_rn(float2{b.x, b.y}));
  r.w = bf2i(__float22bfloat162_rn(float2{b.z, b.w}));
  return r;
}

__device__ __forceinline__ unsigned short f2bf(float f) {
  __hip_bfloat16 h = __float2bfloat16(f);
  unsigned short r; __builtin_memcpy(&r, &h, 2); return r;
}

__device__ __forceinline__ f32x4 mfma16(s16x8 a, s16x8 b, f32x4 c) {
  return __builtin_amdgcn_mfma_f32_16x16x32_bf16(a, b, c, 0, 0, 0);
}

// async global->LDS 16B per lane; LDS dest = wave-uniform base + lane*16
__device__ __forceinline__ void dma16(const unsigned short* g, unsigned short* l) {
  __builtin_amdgcn_global_load_lds((const __attribute__((address_space(1))) u32*)g,
                                   (__attribute__((address_space(3))) u32*)l, 16, 0, 0);
}

// ---------------- weight cast f32 -> bf16 (w1 & w3 only; grid.y picks array) ----------------
__global__ void cast_w2buf(const float* __restrict__ wa, const float* __restrict__ wb,
                           unsigned short* __restrict__ oa, unsigned short* __restrict__ ob,
                           int n8) {
  const float* in = (blockIdx.y == 0) ? wa : wb;
  unsigned short* out = (blockIdx.y == 0) ? oa : ob;
  int i = blockIdx.x * blockDim.x + threadIdx.x;
  const int stride = gridDim.x * blockDim.x;
  for (; i < n8; i += stride) {
    const float4 a = ((const float4*)in)[2 * i];
    const float4 b = ((const float4*)in)[2 * i + 1];
    ((int4*)out)[i] = pack8(a, b);
  }
}

// ---------------- router (+ fused x->bf16 cast) ----------------
__global__ void router_kernel(const float* __restrict__ x, const float* __restrict__ gw,
                              float* __restrict__ logits, int* __restrict__ tk_idx,
                              float* __restrict__ tk_w, unsigned short* __restrict__ xb) {
  __shared__ float xs[H_DIM];
  __shared__ float lg[N_EXP];
  const int t = blockIdx.x;
  const int tid = threadIdx.x;
  const float4 xv = ((const float4*)(x + (size_t)t * H_DIM))[tid];
  ((float4*)xs)[tid] = xv;
  int2 cw;
  cw.x = bf2i(__float22bfloat162_rn(float2{xv.x, xv.y}));
  cw.y = bf2i(__float22bfloat162_rn(float2{xv.z, xv.w}));
  ((int2*)(xb + (size_t)t * H_DIM))[tid] = cw;
  __syncthreads();
  const int w = tid >> 6, l = tid & 63;
  const float* g = gw + w * H_DIM;
  float s = 0.f;
  for (int j = l; j < H_DIM; j += 64) s += xs[j] * g[j];
#pragma unroll
  for (int o = 32; o; o >>= 1) s += __shfl_down(s, o);
  if (l == 0) lg[w] = s;
  __syncthreads();
  if (tid == 0) {
    float mx = lg[0];
#pragma unroll
    for (int i = 1; i < N_EXP; i++) mx = fmaxf(mx, lg[i]);
    float p[N_EXP];
#pragma unroll
    for (int i = 0; i < N_EXP; i++) p[i] = __expf(lg[i] - mx);
    int i0 = 0;
#pragma unroll
    for (int i = 1; i < N_EXP; i++) if (p[i] > p[i0]) i0 = i;
    int i1 = (i0 == 0) ? 1 : 0;
#pragma unroll
    for (int i = 0; i < N_EXP; i++) if (i != i0 && p[i] > p[i1]) i1 = i;
    const float ww = p[i0] + p[i1];
    tk_idx[t * 2] = i0; tk_idx[t * 2 + 1] = i1;
    tk_w[t * 2] = p[i0] / ww; tk_w[t * 2 + 1] = p[i1] / ww;
#pragma unroll
    for (int i = 0; i < N_EXP; i++) logits[t * N_EXP + i] = lg[i];
  }
}

// ---------------- deterministic per-expert list build (1 block/expert) ----------------
__global__ void build_lists(const int* __restrict__ tk_idx, const float* __restrict__ tk_w,
                            int* __restrict__ counts, int* __restrict__ entries,
                            float* __restrict__ wlist) {
  const int e = blockIdx.x;
  const int l = threadIdx.x;
  int base = 0;
  for (int t0 = 0; t0 < T_TOK; t0 += 64) {
    const int t = t0 + l;
    int sel = -1; float w = 0.f;
    const int i0 = tk_idx[t * 2], i1 = tk_idx[t * 2 + 1];
    if (i0 == e) { sel = t * 2; w = tk_w[t * 2]; }
    else if (i1 == e) { sel = t * 2 + 1; w = tk_w[t * 2 + 1]; }
    const unsigned long long mask = __ballot(sel >= 0);
    const int pos = base + __popcll(mask & ((1ull << l) - 1ull));
    if (sel >= 0) { entries[e * T_TOK + pos] = sel; wlist[e * T_TOK + pos] = w; }
    base += __popcll(mask);
  }
  if (l == 0) counts[e] = base;
}

// ---------------- dense work-item table ----------------
__global__ void build_items(const int* __restrict__ counts, int* __restrict__ items) {
  if (threadIdx.x == 0) {
    int n = 0;
#pragma unroll
    for (int e = 0; e < N_EXP; e++) {
      const int c = counts[e];
      for (int m0 = 0; m0 < c; m0 += BM) items[1 + n++] = (e << 16) | (m0 / BM);
    }
    items[0] = n;
  }
}

// ---------------- GEMM1: bf16 weights, all-DMA, 2-phase (R19 proven, 94us) ----------------
__global__ __launch_bounds__(512)
void moe_gemm1b(const unsigned short* __restrict__ w1b, const unsigned short* __restrict__ w3b,
                const unsigned short* __restrict__ xb,
                const int* __restrict__ counts, const int* __restrict__ entries,
                const int* __restrict__ items,
                unsigned short* __restrict__ hb) {
  const int lin = blockIdx.x;
  const int virt = (lin & 7) * G1_CHUNK + (lin >> 3);
  const int ix = virt % NITEM;
  const int iy = virt / NITEM;
  if (ix >= items[0]) return;
  const int it = items[1 + ix];
  const int e = it >> 16;
  const int m0 = (it & 0xffff) * BM;
  const int rem = counts[e] - m0;
  const int n0 = iy * BN;

  __shared__ unsigned short sA[2][BM * BK];   // 2 x 16KB
  __shared__ unsigned short sB1[2][BN * BK];  // 2 x 8KB
  __shared__ unsigned short sB3[2][BN * BK];  // 2 x 8KB

  const int tid = threadIdx.x;
  const int lane = tid & 63;
  const int wave = tid >> 6;
  const int wm = wave >> 1, wn = wave & 1;

  const int* elist = entries + e * T_TOK + m0;

  const int gcolb = (((lane & 7) << 4) ^ (((lane >> 3) & 7) << 4));
  const int arow0 = wave * 16 + (lane >> 3);
  const int arow1 = arow0 + 8;
  const int tokA0 = elist[arow0 < rem ? arow0 : 0] >> 1;
  const int tokA1 = elist[arow1 < rem ? arow1 : 0] >> 1;
  const unsigned short* gaA0 = xb + (size_t)tokA0 * H_DIM + (gcolb >> 1);
  const unsigned short* gaA1 = xb + (size_t)tokA1 * H_DIM + (gcolb >> 1);
  const int awA = wave * 1024;  // u16

  const int rB = tid >> 3;
  const int gbcol = ((tid & 7) ^ (rB & 7)) * 8;  // u16
  const unsigned short* gb1 = w1b + ((size_t)e * F_DIM + n0 + rB) * H_DIM + gbcol;
  const unsigned short* gb3 = w3b + ((size_t)e * F_DIM + n0 + rB) * H_DIM + gbcol;
  const int awB = wave * 512;   // u16

  const int rowA0 = wm * 32 + (lane & 15);
  const int rowA1 = rowA0 + 16;
  const int rowB0 = wn * 32 + (lane & 15);
  const int rowB1 = rowB0 + 16;
  const int kb = (lane >> 4) * 16;

  const f32x4 zero = {0.f, 0.f, 0.f, 0.f};
  f32x4 aG[2][2], aU[2][2];
#pragma unroll
  for (int i = 0; i < 2; i++)
#pragma unroll
    for (int j = 0; j < 2; j++) { aG[i][j] = zero; aU[i][j] = zero; }

  // prologue: stage tile 0 -> buf0; drain; barrier
  dma16(gaA0, sA[0] + awA);
  dma16(gaA1, sA[0] + awA + 512);
  dma16(gb1, sB1[0] + awB);
  dma16(gb3, sB3[0] + awB);
  asm volatile("s_waitcnt vmcnt(0)" ::: "memory");
  __builtin_amdgcn_s_barrier();

  const int NT = H_DIM / BK;  // 32
  for (int t = 0; t < NT; ++t) {
    const int cur = t & 1, nxt = cur ^ 1;
    const int kn = (t + 1 < NT) ? (t + 1) * BK : 0;
    dma16(gaA0 + kn, sA[nxt] + awA);
    dma16(gaA1 + kn, sA[nxt] + awA + 512);
    dma16(gb1 + kn, sB1[nxt] + awB);
    dma16(gb3 + kn, sB3[nxt] + awB);
    __builtin_amdgcn_sched_barrier(0);
    __builtin_amdgcn_s_setprio(1);
    const char* aC = (const char*)sA[cur];
    const char* b1C = (const char*)sB1[cur];
    const char* b3C = (const char*)sB3[cur];
#pragma unroll
    for (int kk = 0; kk < 2; kk++) {
      const int kbyte = kk * 64 + kb;
      const s16x8 a0 = *(const s16x8*)(aC + LOFF(rowA0, kbyte));
      const s16x8 a1 = *(const s16x8*)(aC + LOFF(rowA1, kbyte));
      const s16x8 p0 = *(const s16x8*)(b1C + LOFF(rowB0, kbyte));
      const s16x8 p1 = *(const s16x8*)(b1C + LOFF(rowB1, kbyte));
      const s16x8 q0 = *(const s16x8*)(b3C + LOFF(rowB0, kbyte));
      const s16x8 q1 = *(const s16x8*)(b3C + LOFF(rowB1, kbyte));
      aG[0][0] = mfma16(a0, p0, aG[0][0]); aG[0][1] = mfma16(a0, p1, aG[0][1]);
      aG[1][0] = mfma16(a1, p0, aG[1][0]); aG[1][1] = mfma16(a1, p1, aG[1][1]);
      aU[0][0] = mfma16(a0, q0, aU[0][0]); aU[0][1] = mfma16(a0, q1, aU[0][1]);
      aU[1][0] = mfma16(a1, q0, aU[1][0]); aU[1][1] = mfma16(a1, q1, aU[1][1]);
    }
    __builtin_amdgcn_s_setprio(0);
    asm volatile("s_waitcnt vmcnt(0) lgkmcnt(0)" ::: "memory");
    __builtin_amdgcn_s_barrier();
  }

  // epilogue: h = silu(g)*u -> bf16 scatter by entry row
#pragma unroll
  for (int i = 0; i < 2; i++) {
#pragma unroll
    for (int r = 0; r < 4; r++) {
      const int m = wm * 32 + i * 16 + ((lane >> 4) << 2) + r;
      if (m < rem) {
        const int entry = elist[m];
        unsigned short* hp = hb + (size_t)entry * F_DIM + n0 + wn * 32 + (lane & 15);
#pragma unroll
        for (int j = 0; j < 2; j++) {
          const float g = aG[i][j][r];
          const float u = aU[i][j][r];
          hp[j * 16] = f2bf(g / (1.f + __expf(-g)) * u);
        }
      }
    }
  }
}

// ---------------- GEMM2: f32 w2, reg-staged B (R16 proven, ~62us) ----------------
#define G2F_STEP(ARD, AWR, BLR, BLW, RS, KA1_, KB3_)                          \
  {                                                                           \
    asm volatile("s_waitcnt vmcnt(2) lgkmcnt(0)" ::: "memory");               \
    __builtin_amdgcn_s_barrier();                                             \
    *(int4*)((BLW) + offB) = pack8(RS[0], RS[1]);                             \
    {                                                                         \
      const int ka = (KA1_);                                                  \
      dma16(ga0 + ka, (AWR) + aw);                                            \
      dma16(ga1 + ka, (AWR) + aw + 512);                                      \
      const int kbl = (KB3_);                                                 \
      RS[0] = *(const float4*)(pb + kbl);                                     \
      RS[1] = *(const float4*)(pb + kbl + 4);                                 \
    }                                                                         \
    __builtin_amdgcn_sched_barrier(0);                                        \
    __builtin_amdgcn_s_setprio(1);                                            \
    _Pragma("unroll")                                                         \
    for (int kk = 0; kk < 2; kk++) {                                          \
      const int kbyte = kk * 64 + kb;                                         \
      const s16x8 a0 = *(const s16x8*)((const char*)(ARD) + LOFF(rowA0, kbyte)); \
      const s16x8 a1 = *(const s16x8*)((const char*)(ARD) + LOFF(rowA1, kbyte)); \
      const s16x8 f0 = *(const s16x8*)((BLR) + LOFF(rowB0, kbyte));           \
      const s16x8 f1 = *(const s16x8*)((BLR) + LOFF(rowB1, kbyte));           \
      ac[0][0] = mfma16(a0, f0, ac[0][0]); ac[0][1] = mfma16(a0, f1, ac[0][1]); \
      ac[1][0] = mfma16(a1, f0, ac[1][0]); ac[1][1] = mfma16(a1, f1, ac[1][1]); \
    }                                                                         \
    __builtin_amdgcn_s_setprio(0);                                            \
  }

__global__ __launch_bounds__(512)
void moe_gemm2f(const float* __restrict__ w2,
                const unsigned short* __restrict__ hb,
                const int* __restrict__ counts, const int* __restrict__ entries,
                const float* __restrict__ wlist, const int* __restrict__ items,
                float* __restrict__ out) {
  const int lin = blockIdx.x;
  const int virt = (lin & 7) * G2_CHUNK + (lin >> 3);
  const int ix = virt % NITEM;
  const int iy = virt / NITEM;
  if (ix >= items[0]) return;
  const int it = items[1 + ix];
  const int e = it >> 16;
  const int m0 = (it & 0xffff) * BM;
  const int rem = counts[e] - m0;
  const int n0 = iy * BN;

  __shared__ unsigned short sA[2][BM * BK];
  __shared__ unsigned short sB[2][BN * BK];
  char* sb0 = (char*)sB[0]; char* sb1 = (char*)sB[1];

  const int tid = threadIdx.x;
  const int lane = tid & 63;
  const int wave = tid >> 6;
  const int wm = wave >> 1, wn = wave & 1;

  const int* elist = entries + e * T_TOK + m0;
  const float* wl = wlist + e * T_TOK + m0;

  const int r0 = tid >> 3;
  const int gc = tid & 7;
  const float* pb = w2 + ((size_t)e * H_DIM + n0 + r0) * F_DIM + gc * 8;
  const int offB = LOFF(r0, gc * 16);

  const int arow0 = wave * 16 + (lane >> 3);
  const int arow1 = arow0 + 8;
  const int gcolb = (((lane & 7) << 4) ^ (((lane >> 3) & 7) << 4));
  const int enA0 = elist[arow0 < rem ? arow0 : 0];
  const int enA1 = elist[arow1 < rem ? arow1 : 0];
  const unsigned short* ga0 = hb + (size_t)enA0 * F_DIM + (gcolb >> 1);
  const unsigned short* ga1 = hb + (size_t)enA1 * F_DIM + (gcolb >> 1);
  const int aw = wave * 1024;

  const int rowA0 = wm * 32 + (lane & 15);
  const int rowA1 = rowA0 + 16;
  const int rowB0 = wn * 32 + (lane & 15);
  const int rowB1 = rowB0 + 16;
  const int kb = (lane >> 4) * 16;

  const f32x4 zero = {0.f, 0.f, 0.f, 0.f};
  f32x4 ac[2][2];
#pragma unroll
  for (int i = 0; i < 2; i++)
#pragma unroll
    for (int j = 0; j < 2; j++) ac[i][j] = zero;

  float4 s1r[2], s0r[2];
  s1r[0] = *(const float4*)(pb);      s1r[1] = *(const float4*)(pb + 4);
  s0r[0] = *(const float4*)(pb + BK); s0r[1] = *(const float4*)(pb + BK + 4);
  dma16(ga0, sA[0] + aw);
  dma16(ga1, sA[0] + aw + 512);
  asm volatile("s_waitcnt vmcnt(4)" ::: "memory");
  *(int4*)(sb0 + offB) = pack8(s1r[0], s1r[1]);
  s1r[0] = *(const float4*)(pb + 2 * BK); s1r[1] = *(const float4*)(pb + 2 * BK + 4);

  const int NT = F_DIM / BK;
  for (int t = 0; t < NT; t += 2) {
    const int ka1 = (t + 1 < NT) ? (t + 1) * BK : 0;
    const int ka2 = (t + 2 < NT) ? (t + 2) * BK : 0;
    const int kb3 = (t + 3 < NT) ? (t + 3) * BK : 0;
    const int kb4 = (t + 4 < NT) ? (t + 4) * BK : 0;
    G2F_STEP(sA[0], sA[1], sb0, sb1, s0r, ka1, kb3);
    G2F_STEP(sA[1], sA[0], sb1, sb0, s1r, ka2, kb4);
  }

#pragma unroll
  for (int i = 0; i < 2; i++) {
#pragma unroll
    for (int r = 0; r < 4; r++) {
      const int m = wm * 32 + i * 16 + ((lane >> 4) << 2) + r;
      if (m < rem) {
        const int entry = elist[m];
        const int tok = entry >> 1;
        const float wgt = wl[m];
        float* op = out + (size_t)tok * H_DIM + n0 + wn * 32 + (lane & 15);
#pragma unroll
        for (int j = 0; j < 2; j++) atomicAdd(op + j * 16, wgt * ac[i][j][r]);
      }
    }
  }
}

extern "C" void kernel_launch(void* const* d_in, const int* in_sizes, int n_in,
                              void* d_out, int out_size, void* d_ws, size_t ws_size,
                              hipStream_t stream) {
  const float* x  = (const float*)d_in[0];
  const float* gw = (const float*)d_in[1];
  const float* w1 = (const float*)d_in[2];
  const float* w3 = (const float*)d_in[3];
  const float* w2 = (const float*)d_in[4];
  float* out = (float*)d_out;
  float* logits = out + (size_t)T_TOK * H_DIM;

  char* ws = (char*)d_ws;
  size_t off = 0;
  unsigned short* xb = (unsigned short*)(ws + off); off += (size_t)T_TOK * H_DIM * 2;
  unsigned short* hb = (unsigned short*)(ws + off); off += (size_t)T_TOK * 2 * F_DIM * 2;
  int*   tk_idx = (int*)(ws + off);   off += (size_t)T_TOK * 2 * 4;
  float* tk_w   = (float*)(ws + off); off += (size_t)T_TOK * 2 * 4;
  int*   counts = (int*)(ws + off);   off += 256;
  int*   entries = (int*)(ws + off);  off += (size_t)N_EXP * T_TOK * 4;
  float* wlist  = (float*)(ws + off); off += (size_t)N_EXP * T_TOK * 4;
  int*   items  = (int*)(ws + off);   off += 256;
  unsigned short* w1b = (unsigned short*)(ws + off); off += WELEMS * 2;
  unsigned short* w3b = (unsigned short*)(ws + off); off += WELEMS * 2;

  (void)hipMemsetAsync(d_out, 0, (size_t)out_size * sizeof(float), stream);
  const int n8 = (int)(WELEMS / 8);
  cast_w2buf<<<dim3(2048, 2), 256, 0, stream>>>(w1, w3, w1b, w3b, n8);
  router_kernel<<<dim3(T_TOK), 512, 0, stream>>>(x, gw, logits, tk_idx, tk_w, xb);
  build_lists<<<dim3(N_EXP), 64, 0, stream>>>(tk_idx, tk_w, counts, entries, wlist);
  build_items<<<dim3(1), 64, 0, stream>>>(counts, items);
  moe_gemm1b<<<dim3(NITEM * G1_NY), 512, 0, stream>>>(w1b, w3b, xb, counts, entries, items, hb);
  moe_gemm2f<<<dim3(NITEM * G2_NY), 512, 0, stream>>>(w2, hb, counts, entries, wlist, items, out);
}

// Round 22
// 235.148 us; speedup vs baseline: 1.2128x; 1.0960x over previous
//
#include <hip/hip_runtime.h>
#include <hip/hip_bf16.h>

#define T_TOK 2048
#define H_DIM 2048
#define F_DIM 1408
#define N_EXP 8
#define BM 128
#define BN 64
#define BK 64

#define NITEM 40
#define G1_NY (F_DIM / BN)   // 22
#define G2_NY (H_DIM / BN)   // 32
#define G1_CHUNK ((NITEM * G1_NY) / 8)  // 110
#define G2_CHUNK ((NITEM * G2_NY) / 8)  // 160

typedef float f32x4 __attribute__((ext_vector_type(4)));
typedef short s16x8 __attribute__((ext_vector_type(8)));
typedef unsigned int u32;

// swizzled LDS byte offset: rows are 128B (64 bf16); XOR bits[4:6] with row&7
#define LOFF(row, kbyte) (((row) << 7) + ((kbyte) ^ (((row) & 7) << 4)))

__device__ __forceinline__ int bf2i(__hip_bfloat162 h) {
  int r; __builtin_memcpy(&r, &h, 4); return r;
}

__device__ __forceinline__ int4 pack8(float4 a, float4 b) {
  int4 r;
  r.x = bf2i(__float22bfloat162_rn(float2{a.x, a.y}));
  r.y = bf2i(__float22bfloat162_rn(float2{a.z, a.w}));
  r.z = bf2i(__float22bfloat162_rn(float2{b.x, b.y}));
  r.w = bf2i(__float22bfloat162_rn(float2{b.z, b.w}));
  return r;
}

__device__ __forceinline__ unsigned short f2bf(float f) {
  __hip_bfloat16 h = __float2bfloat16(f);
  unsigned short r; __builtin_memcpy(&r, &h, 2); return r;
}

__device__ __forceinline__ f32x4 mfma16(s16x8 a, s16x8 b, f32x4 c) {
  return __builtin_amdgcn_mfma_f32_16x16x32_bf16(a, b, c, 0, 0, 0);
}

// async global->LDS 16B per lane; LDS dest = wave-uniform base + lane*16
__device__ __forceinline__ void dma16(const unsigned short* g, unsigned short* l) {
  __builtin_amdgcn_global_load_lds((const __attribute__((address_space(1))) u32*)g,
                                   (__attribute__((address_space(3))) u32*)l, 16, 0, 0);
}

// ---------------- router (+ fused x->bf16 cast) ----------------
__global__ void router_kernel(const float* __restrict__ x, const float* __restrict__ gw,
                              float* __restrict__ logits, int* __restrict__ tk_idx,
                              float* __restrict__ tk_w, unsigned short* __restrict__ xb) {
  __shared__ float xs[H_DIM];
  __shared__ float lg[N_EXP];
  const int t = blockIdx.x;
  const int tid = threadIdx.x;
  const float4 xv = ((const float4*)(x + (size_t)t * H_DIM))[tid];
  ((float4*)xs)[tid] = xv;
  int2 cw;
  cw.x = bf2i(__float22bfloat162_rn(float2{xv.x, xv.y}));
  cw.y = bf2i(__float22bfloat162_rn(float2{xv.z, xv.w}));
  ((int2*)(xb + (size_t)t * H_DIM))[tid] = cw;
  __syncthreads();
  const int w = tid >> 6, l = tid & 63;
  const float* g = gw + w * H_DIM;
  float s = 0.f;
  for (int j = l; j < H_DIM; j += 64) s += xs[j] * g[j];
#pragma unroll
  for (int o = 32; o; o >>= 1) s += __shfl_down(s, o);
  if (l == 0) lg[w] = s;
  __syncthreads();
  if (tid == 0) {
    float mx = lg[0];
#pragma unroll
    for (int i = 1; i < N_EXP; i++) mx = fmaxf(mx, lg[i]);
    float p[N_EXP];
#pragma unroll
    for (int i = 0; i < N_EXP; i++) p[i] = __expf(lg[i] - mx);
    int i0 = 0;
#pragma unroll
    for (int i = 1; i < N_EXP; i++) if (p[i] > p[i0]) i0 = i;
    int i1 = (i0 == 0) ? 1 : 0;
#pragma unroll
    for (int i = 0; i < N_EXP; i++) if (i != i0 && p[i] > p[i1]) i1 = i;
    const float ww = p[i0] + p[i1];
    tk_idx[t * 2] = i0; tk_idx[t * 2 + 1] = i1;
    tk_w[t * 2] = p[i0] / ww; tk_w[t * 2 + 1] = p[i1] / ww;
#pragma unroll
    for (int i = 0; i < N_EXP; i++) logits[t * N_EXP + i] = lg[i];
  }
}

// ---------------- deterministic per-expert list build (1 block/expert) ----------------
__global__ void build_lists(const int* __restrict__ tk_idx, const float* __restrict__ tk_w,
                            int* __restrict__ counts, int* __restrict__ entries,
                            float* __restrict__ wlist) {
  const int e = blockIdx.x;
  const int l = threadIdx.x;
  int base = 0;
  for (int t0 = 0; t0 < T_TOK; t0 += 64) {
    const int t = t0 + l;
    int sel = -1; float w = 0.f;
    const int i0 = tk_idx[t * 2], i1 = tk_idx[t * 2 + 1];
    if (i0 == e) { sel = t * 2; w = tk_w[t * 2]; }
    else if (i1 == e) { sel = t * 2 + 1; w = tk_w[t * 2 + 1]; }
    const unsigned long long mask = __ballot(sel >= 0);
    const int pos = base + __popcll(mask & ((1ull << l) - 1ull));
    if (sel >= 0) { entries[e * T_TOK + pos] = sel; wlist[e * T_TOK + pos] = w; }
    base += __popcll(mask);
  }
  if (l == 0) counts[e] = base;
}

// ---------------- dense work-item table: items[0]=n, items[1+i]=(e<<16)|mtile ----------------
__global__ void build_items(const int* __restrict__ counts, int* __restrict__ items) {
  if (threadIdx.x == 0) {
    int n = 0;
#pragma unroll
    for (int e = 0; e < N_EXP; e++) {
      const int c = counts[e];
      for (int m0 = 0; m0 < c; m0 += BM) items[1 + n++] = (e << 16) | (m0 / BM);
    }
    items[0] = n;
  }
}

// ---------------- GEMM1 ----------------
// R11/R16 schedule: one barrier/step, write-ahead B double-buffer (in-kernel
// f32->bf16 pack), counted vmcnt, sched_barrier(0) pin, setprio around MFMAs.
#define G1_STEP(ARD, AWR, BLR1, BLW1, BLR3, BLW3, RS1, RS3, KA1_, KB3_)       \
  {                                                                           \
    asm volatile("s_waitcnt vmcnt(4) lgkmcnt(0)" ::: "memory");               \
    __builtin_amdgcn_s_barrier();                                             \
    *(int4*)((BLW1) + offB) = pack8(RS1[0], RS1[1]);                          \
    *(int4*)((BLW3) + offB) = pack8(RS3[0], RS3[1]);                          \
    {                                                                         \
      const int ka = (KA1_);                                                  \
      dma16(ga0 + ka, (AWR) + aw);                                            \
      dma16(ga1 + ka, (AWR) + aw + 512);                                      \
      const int kbl = (KB3_);                                                 \
      RS1[0] = *(const float4*)(pb1 + kbl);                                   \
      RS1[1] = *(const float4*)(pb1 + kbl + 4);                               \
      RS3[0] = *(const float4*)(pb3 + kbl);                                   \
      RS3[1] = *(const float4*)(pb3 + kbl + 4);                               \
    }                                                                         \
    __builtin_amdgcn_sched_barrier(0);                                        \
    __builtin_amdgcn_s_setprio(1);                                            \
    _Pragma("unroll")                                                         \
    for (int kk = 0; kk < 2; kk++) {                                          \
      const int kbyte = kk * 64 + kb;                                         \
      const s16x8 a0 = *(const s16x8*)((const char*)(ARD) + LOFF(rowA0, kbyte)); \
      const s16x8 a1 = *(const s16x8*)((const char*)(ARD) + LOFF(rowA1, kbyte)); \
      const s16x8 p0 = *(const s16x8*)((BLR1) + LOFF(rowB0, kbyte));          \
      const s16x8 p1 = *(const s16x8*)((BLR1) + LOFF(rowB1, kbyte));          \
      const s16x8 q0 = *(const s16x8*)((BLR3) + LOFF(rowB0, kbyte));          \
      const s16x8 q1 = *(const s16x8*)((BLR3) + LOFF(rowB1, kbyte));          \
      aG[0][0] = mfma16(a0, p0, aG[0][0]); aG[0][1] = mfma16(a0, p1, aG[0][1]); \
      aG[1][0] = mfma16(a1, p0, aG[1][0]); aG[1][1] = mfma16(a1, p1, aG[1][1]); \
      aU[0][0] = mfma16(a0, q0, aU[0][0]); aU[0][1] = mfma16(a0, q1, aU[0][1]); \
      aU[1][0] = mfma16(a1, q0, aU[1][0]); aU[1][1] = mfma16(a1, q1, aU[1][1]); \
    }                                                                         \
    __builtin_amdgcn_s_setprio(0);                                            \
  }

__global__ __launch_bounds__(512)
void moe_gemm1(const float* __restrict__ w1, const float* __restrict__ w3,
               const unsigned short* __restrict__ xb,
               const int* __restrict__ counts, const int* __restrict__ entries,
               const int* __restrict__ items,
               unsigned short* __restrict__ hb) {
  const int lin = blockIdx.x;
  const int virt = (lin & 7) * G1_CHUNK + (lin >> 3);
  const int ix = virt % NITEM;
  const int iy = virt / NITEM;
  if (ix >= items[0]) return;
  const int it = items[1 + ix];
  const int e = it >> 16;
  const int m0 = (it & 0xffff) * BM;
  const int rem = counts[e] - m0;
  const int n0 = iy * BN;

  __shared__ unsigned short sA[2][BM * BK];   // 2 x 16KB
  __shared__ unsigned short sB1[2][BN * BK];  // 2 x 8KB
  __shared__ unsigned short sB3[2][BN * BK];  // 2 x 8KB
  char* sb10 = (char*)sB1[0]; char* sb11 = (char*)sB1[1];
  char* sb30 = (char*)sB3[0]; char* sb31 = (char*)sB3[1];

  const int tid = threadIdx.x;
  const int lane = tid & 63;
  const int wave = tid >> 6;
  const int wm = wave >> 1, wn = wave & 1;

  const int* elist = entries + e * T_TOK + m0;

  const int r0 = tid >> 3;
  const int gc = tid & 7;
  const float* pb1 = w1 + ((size_t)e * F_DIM + n0 + r0) * H_DIM + gc * 8;
  const float* pb3 = w3 + ((size_t)e * F_DIM + n0 + r0) * H_DIM + gc * 8;
  const int offB = LOFF(r0, gc * 16);

  const int arow0 = wave * 16 + (lane >> 3);
  const int arow1 = arow0 + 8;
  const int gcolb = (((lane & 7) << 4) ^ (((lane >> 3) & 7) << 4));
  const int tokA0 = elist[arow0 < rem ? arow0 : 0] >> 1;
  const int tokA1 = elist[arow1 < rem ? arow1 : 0] >> 1;
  const unsigned short* ga0 = xb + (size_t)tokA0 * H_DIM + (gcolb >> 1);
  const unsigned short* ga1 = xb + (size_t)tokA1 * H_DIM + (gcolb >> 1);
  const int aw = wave * 1024;  // u16 elems: wave*2048B

  const int rowA0 = wm * 32 + (lane & 15);
  const int rowA1 = rowA0 + 16;
  const int rowB0 = wn * 32 + (lane & 15);
  const int rowB1 = rowB0 + 16;
  const int kb = (lane >> 4) * 16;

  const f32x4 zero = {0.f, 0.f, 0.f, 0.f};
  f32x4 aG[2][2], aU[2][2];
#pragma unroll
  for (int i = 0; i < 2; i++)
#pragma unroll
    for (int j = 0; j < 2; j++) { aG[i][j] = zero; aU[i][j] = zero; }

  // prologue: s1<-B(0)[4]; s0<-B(1)[4]; dmaA(0)[2]; vmcnt(6) drains s1;
  // BL[0]<-s1; s1<-B(2)[4].  queue: [s0 B(1)x4, dmaA(0)x2, s1 B(2)x4] = 10.
  float4 s1_1[2], s1_3[2], s0_1[2], s0_3[2];
  s1_1[0] = *(const float4*)(pb1);      s1_1[1] = *(const float4*)(pb1 + 4);
  s1_3[0] = *(const float4*)(pb3);      s1_3[1] = *(const float4*)(pb3 + 4);
  s0_1[0] = *(const float4*)(pb1 + BK); s0_1[1] = *(const float4*)(pb1 + BK + 4);
  s0_3[0] = *(const float4*)(pb3 + BK); s0_3[1] = *(const float4*)(pb3 + BK + 4);
  dma16(ga0, sA[0] + aw);
  dma16(ga1, sA[0] + aw + 512);
  asm volatile("s_waitcnt vmcnt(6)" ::: "memory");
  *(int4*)(sb10 + offB) = pack8(s1_1[0], s1_1[1]);
  *(int4*)(sb30 + offB) = pack8(s1_3[0], s1_3[1]);
  s1_1[0] = *(const float4*)(pb1 + 2 * BK); s1_1[1] = *(const float4*)(pb1 + 2 * BK + 4);
  s1_3[0] = *(const float4*)(pb3 + 2 * BK); s1_3[1] = *(const float4*)(pb3 + 2 * BK + 4);

  const int NT = H_DIM / BK;  // 32 (even)
  for (int t = 0; t < NT; t += 2) {
    const int ka1 = (t + 1 < NT) ? (t + 1) * BK : 0;
    const int ka2 = (t + 2 < NT) ? (t + 2) * BK : 0;
    const int kb3 = (t + 3 < NT) ? (t + 3) * BK : 0;
    const int kb4 = (t + 4 < NT) ? (t + 4) * BK : 0;
    G1_STEP(sA[0], sA[1], sb10, sb11, sb30, sb31, s0_1, s0_3, ka1, kb3);
    G1_STEP(sA[1], sA[0], sb11, sb10, sb31, sb30, s1_1, s1_3, ka2, kb4);
  }

  // epilogue: h = silu(g)*u -> bf16 scatter by entry row
#pragma unroll
  for (int i = 0; i < 2; i++) {
#pragma unroll
    for (int r = 0; r < 4; r++) {
      const int m = wm * 32 + i * 16 + ((lane >> 4) << 2) + r;
      if (m < rem) {
        const int entry = elist[m];
        unsigned short* hp = hb + (size_t)entry * F_DIM + n0 + wn * 32 + (lane & 15);
#pragma unroll
        for (int j = 0; j < 2; j++) {
          const float g = aG[i][j][r];
          const float u = aU[i][j][r];
          hp[j * 16] = f2bf(g / (1.f + __expf(-g)) * u);
        }
      }
    }
  }
}

// ---------------- GEMM2 ----------------
#define G2_STEP(ARD, AWR, BLR, BLW, RS, KA1_, KB3_)                           \
  {                                                                           \
    asm volatile("s_waitcnt vmcnt(2) lgkmcnt(0)" ::: "memory");               \
    __builtin_amdgcn_s_barrier();                                             \
    *(int4*)((BLW) + offB) = pack8(RS[0], RS[1]);                             \
    {                                                                         \
      const int ka = (KA1_);                                                  \
      dma16(ga0 + ka, (AWR) + aw);                                            \
      dma16(ga1 + ka, (AWR) + aw + 512);                                      \
      const int kbl = (KB3_);                                                 \
      RS[0] = *(const float4*)(pb + kbl);                                     \
      RS[1] = *(const float4*)(pb + kbl + 4);                                 \
    }                                                                         \
    __builtin_amdgcn_sched_barrier(0);                                        \
    __builtin_amdgcn_s_setprio(1);                                            \
    _Pragma("unroll")                                                         \
    for (int kk = 0; kk < 2; kk++) {                                          \
      const int kbyte = kk * 64 + kb;                                         \
      const s16x8 a0 = *(const s16x8*)((const char*)(ARD) + LOFF(rowA0, kbyte)); \
      const s16x8 a1 = *(const s16x8*)((const char*)(ARD) + LOFF(rowA1, kbyte)); \
      const s16x8 f0 = *(const s16x8*)((BLR) + LOFF(rowB0, kbyte));           \
      const s16x8 f1 = *(const s16x8*)((BLR) + LOFF(rowB1, kbyte));           \
      ac[0][0] = mfma16(a0, f0, ac[0][0]); ac[0][1] = mfma16(a0, f1, ac[0][1]); \
      ac[1][0] = mfma16(a1, f0, ac[1][0]); ac[1][1] = mfma16(a1, f1, ac[1][1]); \
    }                                                                         \
    __builtin_amdgcn_s_setprio(0);                                            \
  }

__global__ __launch_bounds__(512)
void moe_gemm2(const float* __restrict__ w2,
               const unsigned short* __restrict__ hb,
               const int* __restrict__ counts, const int* __restrict__ entries,
               const float* __restrict__ wlist, const int* __restrict__ items,
               float* __restrict__ out) {
  const int lin = blockIdx.x;
  const int virt = (lin & 7) * G2_CHUNK + (lin >> 3);
  const int ix = virt % NITEM;
  const int iy = virt / NITEM;
  if (ix >= items[0]) return;
  const int it = items[1 + ix];
  const int e = it >> 16;
  const int m0 = (it & 0xffff) * BM;
  const int rem = counts[e] - m0;
  const int n0 = iy * BN;

  __shared__ unsigned short sA[2][BM * BK];  // 2 x 16KB
  __shared__ unsigned short sB[2][BN * BK];  // 2 x 8KB
  char* sb0 = (char*)sB[0]; char* sb1 = (char*)sB[1];

  const int tid = threadIdx.x;
  const int lane = tid & 63;
  const int wave = tid >> 6;
  const int wm = wave >> 1, wn = wave & 1;

  const int* elist = entries + e * T_TOK + m0;
  const float* wl = wlist + e * T_TOK + m0;

  const int r0 = tid >> 3;
  const int gc = tid & 7;
  const float* pb = w2 + ((size_t)e * H_DIM + n0 + r0) * F_DIM + gc * 8;
  const int offB = LOFF(r0, gc * 16);

  const int arow0 = wave * 16 + (lane >> 3);
  const int arow1 = arow0 + 8;
  const int gcolb = (((lane & 7) << 4) ^ (((lane >> 3) & 7) << 4));
  const int enA0 = elist[arow0 < rem ? arow0 : 0];
  const int enA1 = elist[arow1 < rem ? arow1 : 0];
  const unsigned short* ga0 = hb + (size_t)enA0 * F_DIM + (gcolb >> 1);
  const unsigned short* ga1 = hb + (size_t)enA1 * F_DIM + (gcolb >> 1);
  const int aw = wave * 1024;

  const int rowA0 = wm * 32 + (lane & 15);
  const int rowA1 = rowA0 + 16;
  const int rowB0 = wn * 32 + (lane & 15);
  const int rowB1 = rowB0 + 16;
  const int kb = (lane >> 4) * 16;

  const f32x4 zero = {0.f, 0.f, 0.f, 0.f};
  f32x4 ac[2][2];
#pragma unroll
  for (int i = 0; i < 2; i++)
#pragma unroll
    for (int j = 0; j < 2; j++) ac[i][j] = zero;

  // prologue: s1<-B(0)[2]; s0<-B(1)[2]; dmaA(0)[2]; vmcnt(4) drains s1;
  // BL[0]<-s1; s1<-B(2)[2].  queue: [s0x2, dmax2, s1x2] = 6.
  float4 s1r[2], s0r[2];
  s1r[0] = *(const float4*)(pb);      s1r[1] = *(const float4*)(pb + 4);
  s0r[0] = *(const float4*)(pb + BK); s0r[1] = *(const float4*)(pb + BK + 4);
  dma16(ga0, sA[0] + aw);
  dma16(ga1, sA[0] + aw + 512);
  asm volatile("s_waitcnt vmcnt(4)" ::: "memory");
  *(int4*)(sb0 + offB) = pack8(s1r[0], s1r[1]);
  s1r[0] = *(const float4*)(pb + 2 * BK); s1r[1] = *(const float4*)(pb + 2 * BK + 4);

  const int NT = F_DIM / BK;  // 22 (even)
  for (int t = 0; t < NT; t += 2) {
    const int ka1 = (t + 1 < NT) ? (t + 1) * BK : 0;
    const int ka2 = (t + 2 < NT) ? (t + 2) * BK : 0;
    const int kb3 = (t + 3 < NT) ? (t + 3) * BK : 0;
    const int kb4 = (t + 4 < NT) ? (t + 4) * BK : 0;
    G2_STEP(sA[0], sA[1], sb0, sb1, s0r, ka1, kb3);
    G2_STEP(sA[1], sA[0], sb1, sb0, s1r, ka2, kb4);
  }

#pragma unroll
  for (int i = 0; i < 2; i++) {
#pragma unroll
    for (int r = 0; r < 4; r++) {
      const int m = wm * 32 + i * 16 + ((lane >> 4) << 2) + r;
      if (m < rem) {
        const int entry = elist[m];
        const int tok = entry >> 1;
        const float wgt = wl[m];
        float* op = out + (size_t)tok * H_DIM + n0 + wn * 32 + (lane & 15);
#pragma unroll
        for (int j = 0; j < 2; j++) atomicAdd(op + j * 16, wgt * ac[i][j][r]);
      }
    }
  }
}

extern "C" void kernel_launch(void* const* d_in, const int* in_sizes, int n_in,
                              void* d_out, int out_size, void* d_ws, size_t ws_size,
                              hipStream_t stream) {
  const float* x  = (const float*)d_in[0];
  const float* gw = (const float*)d_in[1];
  const float* w1 = (const float*)d_in[2];
  const float* w3 = (const float*)d_in[3];
  const float* w2 = (const float*)d_in[4];
  float* out = (float*)d_out;
  float* logits = out + (size_t)T_TOK * H_DIM;

  char* ws = (char*)d_ws;
  size_t off = 0;
  unsigned short* xb = (unsigned short*)(ws + off); off += (size_t)T_TOK * H_DIM * 2;      // 8 MB
  unsigned short* hb = (unsigned short*)(ws + off); off += (size_t)T_TOK * 2 * F_DIM * 2;  // 11.5 MB
  int*   tk_idx = (int*)(ws + off);   off += (size_t)T_TOK * 2 * 4;
  float* tk_w   = (float*)(ws + off); off += (size_t)T_TOK * 2 * 4;
  int*   counts = (int*)(ws + off);   off += 256;
  int*   entries = (int*)(ws + off);  off += (size_t)N_EXP * T_TOK * 4;
  float* wlist  = (float*)(ws + off); off += (size_t)N_EXP * T_TOK * 4;
  int*   items  = (int*)(ws + off);   off += 256;

  (void)hipMemsetAsync(d_out, 0, (size_t)out_size * sizeof(float), stream);
  router_kernel<<<dim3(T_TOK), 512, 0, stream>>>(x, gw, logits, tk_idx, tk_w, xb);
  build_lists<<<dim3(N_EXP), 64, 0, stream>>>(tk_idx, tk_w, counts, entries, wlist);
  build_items<<<dim3(1), 64, 0, stream>>>(counts, items);
  moe_gemm1<<<dim3(NITEM * G1_NY), 512, 0, stream>>>(w1, w3, xb, counts, entries, items, hb);
  moe_gemm2<<<dim3(NITEM * G2_NY), 512, 0, stream>>>(w2, hb, counts, entries, wlist, items, out);
}